// Round 1
// baseline (1160.882 us; speedup 1.0000x reference)
//
#include <hip/hip_runtime.h>

// ---------------------------------------------------------------------------
// Elman RNN (B=64, T=512, H=512, V=50257, O=4), faithful to the JAX reference
// (including softmax-before-CE bug).
//
// Decomposition:
//   K1 convert_w : W_in, W_h fp32 -> f16 scratch (one-time).
//   K2 gemm_pre  : pre[t,b,:] = f16( emb[ids[b,t]] @ W_in^T + b_h )  via MFMA
//                  16x16x32 f16 (layout per learn_hip m89/m91: C/D col=lane&15,
//                  row=(lane>>4)*4+reg; A/B loaded from row-major A and B^T).
//   K3 rnn_steps : 64 WGs (1 batch row / CU), 512 threads (thread j = output
//                  col j). W_h f16 fully CU-resident: 192 VGPRs/thread
//                  (k<384) + 128 KB XOR-swizzled LDS (k>=384). h lives in LDS
//                  as f16 pairs, double-buffered; uniform ds_read_b128
//                  broadcasts it to all waves. One __syncthreads per step.
//   K4 tail      : logits = softmax(h_T @ W_out^T + b_out); loss =
//                  -mean(log_softmax(logits)[label]). out = [loss, logits].
// ---------------------------------------------------------------------------

typedef _Float16 f16;
typedef _Float16 half2_t __attribute__((ext_vector_type(2)));
typedef _Float16 half8_t __attribute__((ext_vector_type(8)));
typedef float f32x4 __attribute__((ext_vector_type(4)));

#define HDIM 512
#define BATCH 64
#define TSTEPS 512
#define OUTC 4

__device__ __forceinline__ float dot2f(unsigned int h, unsigned int w, float acc) {
#if __has_builtin(__builtin_amdgcn_fdot2)
  return __builtin_amdgcn_fdot2(__builtin_bit_cast(half2_t, h),
                                __builtin_bit_cast(half2_t, w), acc, false);
#else
  half2_t a = __builtin_bit_cast(half2_t, h);
  half2_t b = __builtin_bit_cast(half2_t, w);
  return acc + (float)a.x * (float)b.x + (float)a.y * (float)b.y;
#endif
}

// ---- K1: fp32 -> f16 weight conversion -------------------------------------
__global__ void convert_w(const float* __restrict__ Win, const float* __restrict__ Wh,
                          f16* __restrict__ wif, f16* __restrict__ whf) {
  int i = blockIdx.x * 256 + threadIdx.x;
  if (i < HDIM * HDIM) {
    wif[i] = (f16)Win[i];
    whf[i] = (f16)Wh[i];
  }
}

// ---- K2: pre[t*64+b][j] = emb[ids[b,t]] @ W_in^T + b_h  (MFMA f16) ---------
// Row r = t*64 + b so that step t reads 64 contiguous rows.
__global__ __launch_bounds__(256) void gemm_pre(const int* __restrict__ ids,
                                                const float* __restrict__ emb,
                                                const f16* __restrict__ wif,
                                                const float* __restrict__ bh,
                                                f16* __restrict__ preh) {
  // A/B tiles 64x32 f16, stride padded to 40 halves (80 B, 16B-aligned rows,
  // 2-way-max bank pattern on frag reads).
  __shared__ __align__(16) f16 Al[64][40];
  __shared__ __align__(16) f16 Bl[64][40];

  const int tid = threadIdx.x;
  const int rb = blockIdx.x;  // M block (64 rows)
  const int nb = blockIdx.y;  // N block (64 cols)
  const int w = tid >> 6;     // wave 0..3 -> m-subtile
  const int l = tid & 63;

  f32x4 acc[4] = {};  // 4 n-tiles of 16 cols each

  const int srow = tid >> 2;   // staging row 0..63
  const int quad = tid & 3;    // 8-half chunk 0..3

  for (int k0 = 0; k0 < HDIM; k0 += 32) {
    // stage A: gather emb row, convert f32->f16
    {
      int rg = rb * 64 + srow;                    // global token row = t*64+b
      int id = ids[(rg & 63) * TSTEPS + (rg >> 6)];  // ids[b][t], [B][T] layout
      const float4* s = (const float4*)(emb + id * HDIM + k0 + quad * 8);
      float4 a0 = s[0], a1 = s[1];
      half8_t v;
      v[0] = (f16)a0.x; v[1] = (f16)a0.y; v[2] = (f16)a0.z; v[3] = (f16)a0.w;
      v[4] = (f16)a1.x; v[5] = (f16)a1.y; v[6] = (f16)a1.z; v[7] = (f16)a1.w;
      *(half8_t*)&Al[srow][quad * 8] = v;
    }
    // stage B: W_in^T rows (row-major W_in[j][k] is exactly B^T)
    {
      const uint4* s = (const uint4*)(wif + (nb * 64 + srow) * HDIM + k0 + quad * 8);
      *(uint4*)&Bl[srow][quad * 8] = s[0];
    }
    __syncthreads();

    half8_t af = *(const half8_t*)&Al[w * 16 + (l & 15)][(l >> 4) * 8];
#pragma unroll
    for (int nt = 0; nt < 4; ++nt) {
      half8_t bf = *(const half8_t*)&Bl[nt * 16 + (l & 15)][(l >> 4) * 8];
      acc[nt] = __builtin_amdgcn_mfma_f32_16x16x32_f16(af, bf, acc[nt], 0, 0, 0);
    }
    __syncthreads();
  }

  // epilogue: C/D mapping col=lane&15, row=(lane>>4)*4+i  (m89-verified)
#pragma unroll
  for (int nt = 0; nt < 4; ++nt) {
#pragma unroll
    for (int i = 0; i < 4; ++i) {
      int r = rb * 64 + w * 16 + (l >> 4) * 4 + i;
      int c = nb * 64 + nt * 16 + (l & 15);
      preh[r * HDIM + c] = (f16)(acc[nt][i] + bh[c]);
    }
  }
}

// ---- K3: the 512-step recurrence, one batch row per CU ---------------------
__global__ __launch_bounds__(512, 2) void rnn_steps(const f16* __restrict__ preh,
                                                    const f16* __restrict__ whf,
                                                    float* __restrict__ hT) {
  __shared__ __align__(16) uint4 wlds[HDIM * 16];          // 128 KB: k in [384,512)
  __shared__ __align__(16) unsigned int hb[2][HDIM / 2];   // h as f16 pairs, dbuf

  const int j = threadIdx.x;   // output column
  const int b = blockIdx.x;    // batch row

  // Fill swizzled LDS weights: row j, 16B granule c stored at (c ^ (j&15)).
  // Without the XOR, frag reads (lane = consecutive rows, 256 B stride) would
  // be a 64-way bank conflict.
  for (int q = 0; q < 16; ++q) {
    int idx = q * 512 + j;          // 0..8191 over 512 rows x 16 granules
    int row = idx >> 4, c = idx & 15;
    uint4 v = *(const uint4*)(whf + row * HDIM + 384 + c * 8);
    wlds[row * 16 + (c ^ (row & 15))] = v;
  }
  // VGPR-resident weights: W_h[j][0:384) = 48 uint4 = 192 VGPRs.
  uint4 wr[48];
  {
    const uint4* wrow = (const uint4*)(whf + j * HDIM);
#pragma unroll
    for (int c = 0; c < 48; ++c) wr[c] = wrow[c];
  }
  if (j < HDIM / 2) hb[0][j] = 0u;  // h0 = 0
  __syncthreads();

  float pre_cur = (float)preh[b * HDIM + j];  // t = 0
  for (int t = 0; t < TSTEPS; ++t) {
    // prefetch next step's pre to hide HBM latency under the dot loop
    float pre_next = 0.f;
    if (t < TSTEPS - 1) pre_next = (float)preh[((t + 1) * BATCH + b) * HDIM + j];

    const uint4* hp = (const uint4*)hb[t & 1];
    float acc = pre_cur;
#pragma unroll
    for (int c = 0; c < 48; ++c) {      // k in [0,384): weights from VGPRs
      uint4 h4 = hp[c];                 // uniform-address broadcast read
      acc = dot2f(h4.x, wr[c].x, acc);
      acc = dot2f(h4.y, wr[c].y, acc);
      acc = dot2f(h4.z, wr[c].z, acc);
      acc = dot2f(h4.w, wr[c].w, acc);
    }
    const uint4* wl = &wlds[j * 16];
    const int sw = j & 15;
#pragma unroll
    for (int c = 0; c < 16; ++c) {      // k in [384,512): weights from LDS
      uint4 h4 = hp[48 + c];
      uint4 w4 = wl[c ^ sw];
      acc = dot2f(h4.x, w4.x, acc);
      acc = dot2f(h4.y, w4.y, acc);
      acc = dot2f(h4.z, w4.z, acc);
      acc = dot2f(h4.w, w4.w, acc);
    }
    acc = fmaxf(acc, 0.f);
    ((f16*)hb[(t + 1) & 1])[j] = (f16)acc;     // publish h for next step
    if (t == TSTEPS - 1) hT[b * HDIM + j] = acc;
    pre_cur = pre_next;
    __syncthreads();   // one barrier/step: next step reads hb[(t+1)&1]
  }
}

// ---- K4: logits + softmax + log_softmax + NLL ------------------------------
__global__ void tail_kernel(const float* __restrict__ hT, const float* __restrict__ Wout,
                            const float* __restrict__ bout, const int* __restrict__ labels,
                            float* __restrict__ out) {
  __shared__ float lred[BATCH];
  const int b = threadIdx.x;  // 64 threads, 1 wave
  const float4* hr = (const float4*)(hT + b * HDIM);
  const float4* w0 = (const float4*)(Wout + 0 * HDIM);
  const float4* w1 = (const float4*)(Wout + 1 * HDIM);
  const float4* w2 = (const float4*)(Wout + 2 * HDIM);
  const float4* w3 = (const float4*)(Wout + 3 * HDIM);
  float z0 = bout[0], z1 = bout[1], z2 = bout[2], z3 = bout[3];
#pragma unroll 4
  for (int k = 0; k < HDIM / 4; ++k) {
    float4 h = hr[k];
    float4 a = w0[k], c = w1[k], d = w2[k], e = w3[k];
    z0 += h.x * a.x + h.y * a.y + h.z * a.z + h.w * a.w;
    z1 += h.x * c.x + h.y * c.y + h.z * c.z + h.w * c.w;
    z2 += h.x * d.x + h.y * d.y + h.z * d.z + h.w * d.w;
    z3 += h.x * e.x + h.y * e.y + h.z * e.z + h.w * e.w;
  }
  // softmax (the reference's faithful "bug": softmax before CE)
  float m = fmaxf(fmaxf(z0, z1), fmaxf(z2, z3));
  float e0 = __expf(z0 - m), e1 = __expf(z1 - m), e2 = __expf(z2 - m), e3 = __expf(z3 - m);
  float se = e0 + e1 + e2 + e3;
  float p0 = e0 / se, p1 = e1 / se, p2 = e2 / se, p3 = e3 / se;
  // log_softmax over the probabilities
  float m2 = fmaxf(fmaxf(p0, p1), fmaxf(p2, p3));
  float s2 = __expf(p0 - m2) + __expf(p1 - m2) + __expf(p2 - m2) + __expf(p3 - m2);
  float lse = m2 + __logf(s2);
  int lab = labels[b];
  float pl = (lab == 0) ? p0 : (lab == 1) ? p1 : (lab == 2) ? p2 : p3;
  lred[b] = pl - lse;
  out[1 + b * 4 + 0] = p0;
  out[1 + b * 4 + 1] = p1;
  out[1 + b * 4 + 2] = p2;
  out[1 + b * 4 + 3] = p3;
  __syncthreads();
  if (b == 0) {
    float s = 0.f;
#pragma unroll
    for (int i = 0; i < BATCH; ++i) s += lred[i];
    out[0] = -s / (float)BATCH;
  }
}

// ---------------------------------------------------------------------------
extern "C" void kernel_launch(void* const* d_in, const int* in_sizes, int n_in,
                              void* d_out, int out_size, void* d_ws, size_t ws_size,
                              hipStream_t stream) {
  const int* ids = (const int*)d_in[0];
  const int* labels = (const int*)d_in[1];
  const float* emb = (const float*)d_in[2];
  const float* Win = (const float*)d_in[3];
  const float* Wh = (const float*)d_in[4];
  const float* bh = (const float*)d_in[5];
  const float* Wout = (const float*)d_in[6];
  const float* bout = (const float*)d_in[7];
  float* out = (float*)d_out;

  // ws layout: whf 512K | wif 512K | preh 32M | hT 128K  (~33.7 MB total)
  char* ws = (char*)d_ws;
  f16* whf = (f16*)ws;
  f16* wif = (f16*)(ws + (512 << 10));
  f16* preh = (f16*)(ws + (1 << 20));
  float* hT = (float*)(ws + (1 << 20) + (32 << 20));

  convert_w<<<dim3(1024), dim3(256), 0, stream>>>(Win, Wh, wif, whf);
  gemm_pre<<<dim3(512, 8), dim3(256), 0, stream>>>(ids, emb, wif, bh, preh);
  rnn_steps<<<dim3(64), dim3(512), 0, stream>>>(preh, whf, hT);
  tail_kernel<<<dim3(1), dim3(64), 0, stream>>>(hT, Wout, bout, labels, out);
}